// Round 2
// baseline (290.255 us; speedup 1.0000x reference)
//
#include <hip/hip_runtime.h>
#include <cstdint>

#define HEADS 8
#define HD 64
#define NQ 4096
#define NKV 1024

typedef unsigned short u16;
typedef __attribute__((ext_vector_type(8))) short short8;
typedef __attribute__((ext_vector_type(4))) float f32x4;

__device__ __forceinline__ u16 f2bf(float f){
  union { float f; unsigned u; } c; c.f = f;
  unsigned r = c.u + 0x7fffu + ((c.u >> 16) & 1u);
  return (u16)(r >> 16);
}
__device__ __forceinline__ unsigned pack2(float a, float b){
  return (unsigned)f2bf(a) | ((unsigned)f2bf(b) << 16);
}
__device__ __forceinline__ void gll16(const void* g, void* l){
  __builtin_amdgcn_global_load_lds((const __attribute__((address_space(1))) unsigned*)g,
                                   (__attribute__((address_space(3))) unsigned*)l, 16, 0, 0);
}

// ---- prep: x -> bf16 (both token layout and conv-patch layout) ----
__global__ __launch_bounds__(256) void prep_x(const float* __restrict__ x,
                                              u16* __restrict__ x_bf,
                                              u16* __restrict__ a_conv){
  int tid = blockIdx.x * 256 + threadIdx.x;        // 1,048,576 threads, 8 elems each
  int b   = tid >> 18;
  int rem = tid & 262143;
  int pos = rem >> 6;
  int ci0 = (rem & 63) << 3;
  size_t src = ((size_t)(b * NQ + pos)) * 512 + ci0;
  const float4* s4 = (const float4*)(x + src);
  float4 v0 = s4[0], v1 = s4[1];
  uint4 p;
  p.x = pack2(v0.x, v0.y); p.y = pack2(v0.z, v0.w);
  p.z = pack2(v1.x, v1.y); p.w = pack2(v1.z, v1.w);
  *(uint4*)(x_bf + src) = p;
  int h = pos >> 6, w = pos & 63;
  int pr = (h >> 1) * 32 + (w >> 1);
  int t  = (h & 1) * 2 + (w & 1);
  *(uint4*)(a_conv + ((size_t)(b * NKV + pr)) * 2048 + t * 512 + ci0) = p;
}

// ---- prep: weights -> bf16, transposed to [N][K] ----
__global__ __launch_bounds__(256) void prep_w(const float* __restrict__ q_w,
                                              const float* __restrict__ kv_w,
                                              const float* __restrict__ proj_w,
                                              const float* __restrict__ sr_w,
                                              u16* __restrict__ q_wT, u16* __restrict__ kv_wT,
                                              u16* __restrict__ proj_wT, u16* __restrict__ conv_BT){
  int e = blockIdx.x * 256 + threadIdx.x;          // 2,097,152 total
  if (e < 262144){ int n = e >> 9, k = e & 511; q_wT[e] = f2bf(q_w[k * 512 + n]); return; }
  e -= 262144;
  if (e < 524288){ int n = e >> 9, k = e & 511; kv_wT[e] = f2bf(kv_w[k * 1024 + n]); return; }
  e -= 524288;
  if (e < 262144){ int n = e >> 9, k = e & 511; proj_wT[e] = f2bf(proj_w[k * 512 + n]); return; }
  e -= 262144;
  { int co = e >> 11, r = e & 2047, t = r >> 9, ci = r & 511;
    conv_BT[e] = f2bf(sr_w[co * 2048 + ci * 4 + t]); }
}

// ---- GEMM: C[M,N] = A[M,K] @ BT[N,K]^T,  128x128 tile, BK=32, 4 waves ----
// MODE 0: fp32 out row-major (+bias).  MODE 1: q scatter (bf16, *0.125).  MODE 2: kv scatter.
template<int MODE>
__global__ __launch_bounds__(256) void gemm_bt(const u16* __restrict__ A, const u16* __restrict__ BT,
                                               float* __restrict__ Cf, u16* __restrict__ Cb0,
                                               u16* __restrict__ Cb1, const float* __restrict__ bias,
                                               int M, int N, int K){
  __shared__ __align__(16) u16 As[128 * 32];
  __shared__ __align__(16) u16 Bs[128 * 32];
  const int tid = threadIdx.x, lane = tid & 63, wave = tid >> 6;
  const int m0 = blockIdx.y * 128, n0 = blockIdx.x * 128;
  const int wr = wave >> 1, wc = wave & 1;
  f32x4 acc[4][4] = {};
  for (int kt = 0; kt < K; kt += 32){
    #pragma unroll
    for (int i = 0; i < 2; ++i){
      int c = i * 256 + tid;
      int row = c >> 2, ks = (c & 3) << 3;
      gll16(A  + (size_t)(m0 + row) * K + kt + ks, As + (size_t)(i * 256 + wave * 64) * 8);
      gll16(BT + (size_t)(n0 + row) * K + kt + ks, Bs + (size_t)(i * 256 + wave * 64) * 8);
    }
    __syncthreads();
    short8 af[4];
    #pragma unroll
    for (int mi = 0; mi < 4; ++mi)
      af[mi] = *(const short8*)(As + (wr * 64 + mi * 16 + (lane & 15)) * 32 + (lane >> 4) * 8);
    #pragma unroll
    for (int ni = 0; ni < 4; ++ni){
      short8 bf = *(const short8*)(Bs + (wc * 64 + ni * 16 + (lane & 15)) * 32 + (lane >> 4) * 8);
      #pragma unroll
      for (int mi = 0; mi < 4; ++mi)
        acc[mi][ni] = __builtin_amdgcn_mfma_f32_16x16x32_bf16(af[mi], bf, acc[mi][ni], 0, 0, 0);
    }
    __syncthreads();
  }
  #pragma unroll
  for (int mi = 0; mi < 4; ++mi){
    int row = m0 + wr * 64 + mi * 16 + (lane >> 4) * 4;
    #pragma unroll
    for (int ni = 0; ni < 4; ++ni){
      int col = n0 + wc * 64 + ni * 16 + (lane & 15);
      f32x4 v = acc[mi][ni];
      if (MODE == 0){
        float bb = bias ? bias[col] : 0.f;
        #pragma unroll
        for (int j = 0; j < 4; ++j) Cf[(size_t)(row + j) * N + col] = v[j] + bb;
      } else if (MODE == 1){
        int h = col >> 6, d = col & 63;
        #pragma unroll
        for (int j = 0; j < 4; ++j){
          int r = row + j, b = r >> 12, nq = r & 4095;
          Cb0[(((size_t)(b * HEADS + h)) * NQ + nq) * HD + d] = f2bf(v[j] * 0.125f);
        }
      } else {
        int s = col >> 9, h = (col >> 6) & 7, d = col & 63;
        u16* dst = s ? Cb1 : Cb0;
        #pragma unroll
        for (int j = 0; j < 4; ++j){
          int r = row + j, b = r >> 10, p = r & 1023;
          dst[(((size_t)(b * HEADS + h)) * NKV + p) * HD + d] = f2bf(v[j]);
        }
      }
    }
  }
}

// ---- LayerNorm over 512 cols, fp32 in, bf16 out; one wave per row ----
__global__ __launch_bounds__(256) void ln_k(const float* __restrict__ xp, const float* __restrict__ w,
                                            const float* __restrict__ bias, u16* __restrict__ xr){
  int row = blockIdx.x * 4 + (threadIdx.x >> 6);
  int lane = threadIdx.x & 63;
  const float* src = xp + (size_t)row * 512;
  float vals[8]; float s = 0.f, ss = 0.f;
  #pragma unroll
  for (int j = 0; j < 8; ++j){ float v = src[lane + j * 64]; vals[j] = v; s += v; ss += v * v; }
  #pragma unroll
  for (int off = 32; off >= 1; off >>= 1){ s += __shfl_xor(s, off); ss += __shfl_xor(ss, off); }
  float mean = s * (1.f / 512.f);
  float var  = ss * (1.f / 512.f) - mean * mean;
  float rs = rsqrtf(var + 1e-5f);
  u16* dst = xr + (size_t)row * 512;
  #pragma unroll
  for (int j = 0; j < 8; ++j){
    int c = lane + j * 64;
    dst[c] = f2bf((vals[j] - mean) * rs * w[c] + bias[c]);
  }
}

// ---- flash attention: q pre-scaled; 4 waves x 16 q-rows; KVBLK=64 in LDS ----
__global__ __launch_bounds__(256) void attn_k(const u16* __restrict__ q_s, const u16* __restrict__ k_s,
                                              const u16* __restrict__ v_s, u16* __restrict__ net){
  __shared__ __align__(16) u16 Ks[64 * 72];
  __shared__ __align__(16) u16 Vt[64 * 72];
  __shared__ __align__(16) u16 Ps[4][16 * 72];
  const int tid = threadIdx.x, lane = tid & 63, wave = tid >> 6;
  const int bh = blockIdx.y;
  const u16* kb = k_s + (size_t)bh * NKV * HD;
  const u16* vb = v_s + (size_t)bh * NKV * HD;
  const int q0 = blockIdx.x * 64 + wave * 16;
  const u16* qrow = q_s + ((size_t)bh * NQ + q0 + (lane & 15)) * HD + ((lane >> 4) * 8);
  short8 qf0 = *(const short8*)(qrow);
  short8 qf1 = *(const short8*)(qrow + 32);
  f32x4 o[4] = {};
  float m_run[4], l_run[4];
  #pragma unroll
  for (int j = 0; j < 4; ++j){ m_run[j] = -1e30f; l_run[j] = 0.f; }

  for (int kv0 = 0; kv0 < NKV; kv0 += 64){
    #pragma unroll
    for (int i = 0; i < 2; ++i){               // K tile: 64 rows x 64 cols (8 chunks/row)
      int c = i * 256 + tid;
      int r = c >> 3, ks = (c & 7) << 3;
      short8 dk = *(const short8*)(kb + (size_t)(kv0 + r) * HD + ks);
      *(short8*)(Ks + r * 72 + ks) = dk;
    }
    #pragma unroll
    for (int i = 0; i < 2; ++i){               // V tile, transposed (d-major)
      int c = i * 256 + tid;
      int key = c >> 3, d0 = (c & 7) << 3;
      short8 dv = *(const short8*)(vb + (size_t)(kv0 + key) * HD + d0);
      #pragma unroll
      for (int j = 0; j < 8; ++j) Vt[(d0 + j) * 72 + key] = (u16)dv[j];
    }
    __syncthreads();

    f32x4 sa[4];
    #pragma unroll
    for (int nt = 0; nt < 4; ++nt){
      f32x4 a = {};
      short8 b0 = *(const short8*)(Ks + (nt * 16 + (lane & 15)) * 72 + (lane >> 4) * 8);
      short8 b1 = *(const short8*)(Ks + (nt * 16 + (lane & 15)) * 72 + 32 + (lane >> 4) * 8);
      a = __builtin_amdgcn_mfma_f32_16x16x32_bf16(qf0, b0, a, 0, 0, 0);
      a = __builtin_amdgcn_mfma_f32_16x16x32_bf16(qf1, b1, a, 0, 0, 0);
      sa[nt] = a;
    }
    #pragma unroll
    for (int j = 0; j < 4; ++j){
      float mt = fmaxf(fmaxf(sa[0][j], sa[1][j]), fmaxf(sa[2][j], sa[3][j]));
      #pragma unroll
      for (int off = 8; off >= 1; off >>= 1) mt = fmaxf(mt, __shfl_xor(mt, off));
      float mn = fmaxf(m_run[j], mt);
      float corr = __expf(m_run[j] - mn);
      float ps = 0.f;
      int prow = ((lane >> 4) * 4 + j) * 72 + (lane & 15);
      #pragma unroll
      for (int nt = 0; nt < 4; ++nt){
        float p = __expf(sa[nt][j] - mn);
        ps += p;
        Ps[wave][prow + nt * 16] = f2bf(p);
      }
      #pragma unroll
      for (int off = 8; off >= 1; off >>= 1) ps += __shfl_xor(ps, off);
      l_run[j] = l_run[j] * corr + ps;
      m_run[j] = mn;
      #pragma unroll
      for (int dt = 0; dt < 4; ++dt) o[dt][j] *= corr;
    }
    __syncthreads();                           // Ps visible (and wave-lockstep)
    #pragma unroll
    for (int dt = 0; dt < 4; ++dt){
      #pragma unroll
      for (int ks = 0; ks < 2; ++ks){
        short8 a8 = *(const short8*)(Ps[wave] + (lane & 15) * 72 + ks * 32 + (lane >> 4) * 8);
        short8 b8 = *(const short8*)(Vt + (dt * 16 + (lane & 15)) * 72 + ks * 32 + (lane >> 4) * 8);
        o[dt] = __builtin_amdgcn_mfma_f32_16x16x32_bf16(a8, b8, o[dt], 0, 0, 0);
      }
    }
    __syncthreads();                           // before restaging Ks/Vt
  }
  int b = bh >> 3, h = bh & 7;
  #pragma unroll
  for (int dt = 0; dt < 4; ++dt){
    #pragma unroll
    for (int j = 0; j < 4; ++j){
      int r = q0 + (lane >> 4) * 4 + j;
      float val = o[dt][j] / l_run[j];
      net[((size_t)b * NQ + r) * 512 + h * HD + dt * 16 + (lane & 15)] = f2bf(val);
    }
  }
}

extern "C" void kernel_launch(void* const* d_in, const int* in_sizes, int n_in,
                              void* d_out, int out_size, void* d_ws, size_t ws_size,
                              hipStream_t stream){
  const float* x      = (const float*)d_in[0];
  const float* q_w    = (const float*)d_in[1];
  const float* kv_w   = (const float*)d_in[2];
  const float* proj_w = (const float*)d_in[3];
  const float* proj_b = (const float*)d_in[4];
  const float* sr_w   = (const float*)d_in[5];
  const float* sr_b   = (const float*)d_in[6];
  const float* ln_w   = (const float*)d_in[7];
  const float* ln_b   = (const float*)d_in[8];
  (void)in_sizes; (void)n_in; (void)out_size; (void)ws_size;

  char* ws = (char*)d_ws;
  u16*   x_bf    = (u16*)(ws);                               // 16 MB
  u16*   a_conv  = (u16*)(ws + ((size_t)16 << 20));          // 16 MB (reused by net)
  u16*   net     = (u16*)(ws + ((size_t)16 << 20));
  u16*   q_sb    = (u16*)(ws + ((size_t)32 << 20));          // 16 MB
  float* xr_pre  = (float*)(ws + ((size_t)48 << 20));        // 8 MB (reused by k/v)
  u16*   k_sb    = (u16*)(ws + ((size_t)48 << 20));          // 4 MB
  u16*   v_sb    = (u16*)(ws + ((size_t)52 << 20));          // 4 MB
  u16*   xr      = (u16*)(ws + ((size_t)56 << 20));          // 4 MB
  u16*   q_wT    = (u16*)(ws + ((size_t)60 << 20));
  u16*   kv_wT   = (u16*)(ws + ((size_t)60 << 20) + 524288);
  u16*   proj_wT = (u16*)(ws + ((size_t)60 << 20) + 524288 + 1048576);
  u16*   conv_BT = (u16*)(ws + ((size_t)60 << 20) + 524288 + 1048576 + 524288);
  float* out = (float*)d_out;

  prep_w<<<8192, 256, 0, stream>>>(q_w, kv_w, proj_w, sr_w, q_wT, kv_wT, proj_wT, conv_BT);
  prep_x<<<4096, 256, 0, stream>>>(x, x_bf, a_conv);
  gemm_bt<1><<<dim3(4, 128), 256, 0, stream>>>(x_bf, q_wT, nullptr, q_sb, nullptr, nullptr, 16384, 512, 512);
  gemm_bt<0><<<dim3(4, 32),  256, 0, stream>>>(a_conv, conv_BT, xr_pre, nullptr, nullptr, sr_b, 4096, 512, 2048);
  ln_k<<<1024, 256, 0, stream>>>(xr_pre, ln_w, ln_b, xr);
  gemm_bt<2><<<dim3(8, 32),  256, 0, stream>>>(xr, kv_wT, nullptr, k_sb, v_sb, nullptr, 4096, 1024, 512);
  attn_k<<<dim3(64, 32), 256, 0, stream>>>(q_sb, k_sb, v_sb, net);
  gemm_bt<0><<<dim3(4, 128), 256, 0, stream>>>(net, proj_wT, out, nullptr, nullptr, proj_b, 16384, 512, 512);
}

// Round 3
// 207.045 us; speedup vs baseline: 1.4019x; 1.4019x over previous
//
#include <hip/hip_runtime.h>
#include <cstdint>

#define HEADS 8
#define HD 64
#define NQ 4096
#define NKV 1024

typedef unsigned short u16;
typedef __attribute__((ext_vector_type(8))) short short8;
typedef __attribute__((ext_vector_type(4))) float f32x4;

__device__ __forceinline__ u16 f2bf(float f){
  union { float f; unsigned u; } c; c.f = f;
  unsigned r = c.u + 0x7fffu + ((c.u >> 16) & 1u);
  return (u16)(r >> 16);
}
__device__ __forceinline__ unsigned pack2(float a, float b){
  return (unsigned)f2bf(a) | ((unsigned)f2bf(b) << 16);
}
__device__ __forceinline__ void gll16(const void* g, void* l){
  __builtin_amdgcn_global_load_lds((const __attribute__((address_space(1))) unsigned*)g,
                                   (__attribute__((address_space(3))) unsigned*)l, 16, 0, 0);
}
#define SB0() __builtin_amdgcn_sched_barrier(0)

// ---- prep: x -> bf16 (both token layout and conv-patch layout) ----
__global__ __launch_bounds__(256) void prep_x(const float* __restrict__ x,
                                              u16* __restrict__ x_bf,
                                              u16* __restrict__ a_conv){
  int tid = blockIdx.x * 256 + threadIdx.x;
  int b   = tid >> 18;
  int rem = tid & 262143;
  int pos = rem >> 6;
  int ci0 = (rem & 63) << 3;
  size_t src = ((size_t)(b * NQ + pos)) * 512 + ci0;
  const float4* s4 = (const float4*)(x + src);
  float4 v0 = s4[0], v1 = s4[1];
  uint4 p;
  p.x = pack2(v0.x, v0.y); p.y = pack2(v0.z, v0.w);
  p.z = pack2(v1.x, v1.y); p.w = pack2(v1.z, v1.w);
  *(uint4*)(x_bf + src) = p;
  int h = pos >> 6, w = pos & 63;
  int pr = (h >> 1) * 32 + (w >> 1);
  int t  = (h & 1) * 2 + (w & 1);
  *(uint4*)(a_conv + ((size_t)(b * NKV + pr)) * 2048 + t * 512 + ci0) = p;
}

// ---- prep: weights -> bf16, transposed to [N][K] ----
__global__ __launch_bounds__(256) void prep_w(const float* __restrict__ q_w,
                                              const float* __restrict__ kv_w,
                                              const float* __restrict__ proj_w,
                                              const float* __restrict__ sr_w,
                                              u16* __restrict__ q_wT, u16* __restrict__ kv_wT,
                                              u16* __restrict__ proj_wT, u16* __restrict__ conv_BT){
  int e = blockIdx.x * 256 + threadIdx.x;
  if (e < 262144){ int n = e >> 9, k = e & 511; q_wT[e] = f2bf(q_w[k * 512 + n]); return; }
  e -= 262144;
  if (e < 524288){ int n = e >> 9, k = e & 511; kv_wT[e] = f2bf(kv_w[k * 1024 + n]); return; }
  e -= 524288;
  if (e < 262144){ int n = e >> 9, k = e & 511; proj_wT[e] = f2bf(proj_w[k * 512 + n]); return; }
  e -= 262144;
  { int co = e >> 11, r = e & 2047, t = r >> 9, ci = r & 511;
    conv_BT[e] = f2bf(sr_w[co * 2048 + ci * 4 + t]); }
}

// ---- GEMM: C[M,N] = A[M,K] @ BT[N,K]^T,  128x128 tile, BK=32, 4 waves ----
// MODE 0: fp32 out (+bias).  MODE 1: q scatter (bf16, *0.125).  MODE 2: k scatter + v^T scatter.
template<int MODE>
__global__ __launch_bounds__(256) void gemm_bt(const u16* __restrict__ A, const u16* __restrict__ BT,
                                               float* __restrict__ Cf, u16* __restrict__ Cb0,
                                               u16* __restrict__ Cb1, const float* __restrict__ bias,
                                               int M, int N, int K){
  __shared__ __align__(16) u16 As[128 * 32];
  __shared__ __align__(16) u16 Bs[128 * 32];
  const int tid = threadIdx.x, lane = tid & 63, wave = tid >> 6;
  const int m0 = blockIdx.y * 128, n0 = blockIdx.x * 128;
  const int wr = wave >> 1, wc = wave & 1;
  f32x4 acc[4][4] = {};
  for (int kt = 0; kt < K; kt += 32){
    #pragma unroll
    for (int i = 0; i < 2; ++i){
      int c = i * 256 + tid;
      int row = c >> 2, ks = (c & 3) << 3;
      gll16(A  + (size_t)(m0 + row) * K + kt + ks, As + (size_t)(i * 256 + wave * 64) * 8);
      gll16(BT + (size_t)(n0 + row) * K + kt + ks, Bs + (size_t)(i * 256 + wave * 64) * 8);
    }
    __syncthreads();
    short8 af[4];
    #pragma unroll
    for (int mi = 0; mi < 4; ++mi)
      af[mi] = *(const short8*)(As + (wr * 64 + mi * 16 + (lane & 15)) * 32 + (lane >> 4) * 8);
    #pragma unroll
    for (int ni = 0; ni < 4; ++ni){
      short8 bf = *(const short8*)(Bs + (wc * 64 + ni * 16 + (lane & 15)) * 32 + (lane >> 4) * 8);
      #pragma unroll
      for (int mi = 0; mi < 4; ++mi)
        acc[mi][ni] = __builtin_amdgcn_mfma_f32_16x16x32_bf16(af[mi], bf, acc[mi][ni], 0, 0, 0);
    }
    __syncthreads();
  }
  #pragma unroll
  for (int mi = 0; mi < 4; ++mi){
    int row = m0 + wr * 64 + mi * 16 + (lane >> 4) * 4;
    #pragma unroll
    for (int ni = 0; ni < 4; ++ni){
      int col = n0 + wc * 64 + ni * 16 + (lane & 15);
      f32x4 v = acc[mi][ni];
      if (MODE == 0){
        float bb = bias ? bias[col] : 0.f;
        #pragma unroll
        for (int j = 0; j < 4; ++j) Cf[(size_t)(row + j) * N + col] = v[j] + bb;
      } else if (MODE == 1){
        int h = col >> 6, d = col & 63;
        #pragma unroll
        for (int j = 0; j < 4; ++j){
          int r = row + j, b = r >> 12, nq = r & 4095;
          Cb0[(((size_t)(b * HEADS + h)) * NQ + nq) * HD + d] = f2bf(v[j] * 0.125f);
        }
      } else {
        int s = col >> 9, h = (col >> 6) & 7, d = col & 63;
        if (s == 0){
          #pragma unroll
          for (int j = 0; j < 4; ++j){
            int r = row + j, b = r >> 10, p = r & 1023;
            Cb0[(((size_t)(b * HEADS + h)) * NKV + p) * HD + d] = f2bf(v[j]);
          }
        } else {                               // V^T: [bh][d][p], 4 consecutive p packed
          int b = row >> 10, p0 = row & 1023;
          ushort4 pk;
          pk.x = f2bf(v[0]); pk.y = f2bf(v[1]); pk.z = f2bf(v[2]); pk.w = f2bf(v[3]);
          *(ushort4*)(Cb1 + (((size_t)(b * HEADS + h)) * HD + d) * NKV + p0) = pk;
        }
      }
    }
  }
}

// ---- LayerNorm over 512 cols, fp32 in, bf16 out; one wave per row ----
__global__ __launch_bounds__(256) void ln_k(const float* __restrict__ xp, const float* __restrict__ w,
                                            const float* __restrict__ bias, u16* __restrict__ xr){
  int row = blockIdx.x * 4 + (threadIdx.x >> 6);
  int lane = threadIdx.x & 63;
  const float* src = xp + (size_t)row * 512;
  float vals[8]; float s = 0.f, ss = 0.f;
  #pragma unroll
  for (int j = 0; j < 8; ++j){ float v = src[lane + j * 64]; vals[j] = v; s += v; ss += v * v; }
  #pragma unroll
  for (int off = 32; off >= 1; off >>= 1){ s += __shfl_xor(s, off); ss += __shfl_xor(ss, off); }
  float mean = s * (1.f / 512.f);
  float var  = ss * (1.f / 512.f) - mean * mean;
  float rs = rsqrtf(var + 1e-5f);
  u16* dst = xr + (size_t)row * 512;
  #pragma unroll
  for (int j = 0; j < 8; ++j){
    int c = lane + j * 64;
    dst[c] = f2bf((vals[j] - mean) * rs * w[c] + bias[c]);
  }
}

// ---- flash attention v2: swapped QK^T, in-register softmax, dbuf gll16 staging ----
// grid (64, 32): x = q-block (64 rows, 4 waves x 16), y = bh. q pre-scaled by 1/8.
__global__ __launch_bounds__(256) void attn_k(const u16* __restrict__ q_s, const u16* __restrict__ k_s,
                                              const u16* __restrict__ vt_s, u16* __restrict__ net){
  __shared__ __align__(16) u16 Ks[2][64 * 64];
  __shared__ __align__(16) u16 Vt[2][64 * 64];
  const int tid = threadIdx.x, lane = tid & 63, wave = tid >> 6;
  const int l15 = lane & 15, g = lane >> 4, rx = l15 & 7;
  const int bh = blockIdx.y;
  const u16* kb  = k_s  + (size_t)bh * NKV * HD;
  const u16* vtb = vt_s + (size_t)bh * HD * NKV;
  const int q0 = blockIdx.x * 64 + wave * 16;
  const u16* qrow = q_s + ((size_t)bh * NQ + q0 + l15) * HD + g * 8;
  short8 qf0 = *(const short8*)(qrow);
  short8 qf1 = *(const short8*)(qrow + 32);

  // per-lane pre-swizzled global staging addresses (chunk ^= row&7; LDS stays linear)
  const int swz8 = (((tid & 7) ^ ((tid >> 3) & 7)) << 3);
  const u16* ak0 = kb  + (size_t)(tid >> 3) * 64   + swz8;
  const u16* av0 = vtb + (size_t)(tid >> 3) * 1024 + swz8;

  f32x4 o[4] = {};
  float m_run = -1e30f, l_run = 0.f;

#define STAGE(b2, kv0) do { \
    gll16(ak0 + (size_t)(kv0) * 64,        &Ks[b2][wave * 512]); \
    gll16(ak0 + (size_t)(kv0) * 64 + 2048, &Ks[b2][2048 + wave * 512]); \
    gll16(av0 + (kv0),                     &Vt[b2][wave * 512]); \
    gll16(av0 + (kv0) + 32 * 1024,         &Vt[b2][2048 + wave * 512]); \
  } while (0)

  STAGE(0, 0);
  for (int t = 0; t < 16; ++t){
    const int cur = t & 1;
    SB0();
    if (t < 15){
      STAGE(cur ^ 1, (t + 1) * 64);
      SB0();
      asm volatile("s_waitcnt vmcnt(4)" ::: "memory");
    } else {
      asm volatile("s_waitcnt vmcnt(0)" ::: "memory");
    }
    __builtin_amdgcn_s_barrier();
    SB0();
    const u16* ksb = &Ks[cur][0];
    const u16* vsb = &Vt[cur][0];

    // QK^T swapped: S^T[kv][q] = mfma(K-frag, Q-frag)
    f32x4 sa[4];
    __builtin_amdgcn_s_setprio(1);
    #pragma unroll
    for (int nt = 0; nt < 4; ++nt){
      int r = nt * 16 + l15;
      short8 k0 = *(const short8*)(ksb + r * 64 + ((g ^ rx) << 3));
      short8 k1 = *(const short8*)(ksb + r * 64 + (((4 + g) ^ rx) << 3));
      f32x4 a = {0.f, 0.f, 0.f, 0.f};
      a = __builtin_amdgcn_mfma_f32_16x16x32_bf16(k0, qf0, a, 0, 0, 0);
      a = __builtin_amdgcn_mfma_f32_16x16x32_bf16(k1, qf1, a, 0, 0, 0);
      sa[nt] = a;
    }
    __builtin_amdgcn_s_setprio(0);

    // online softmax, fully in-register (lane owns q = l15; groups hold kv quarters)
    float mt = sa[0][0];
    #pragma unroll
    for (int nt = 0; nt < 4; ++nt)
      #pragma unroll
      for (int j = 0; j < 4; ++j) mt = fmaxf(mt, sa[nt][j]);
    mt = fmaxf(mt, __shfl_xor(mt, 16));
    mt = fmaxf(mt, __shfl_xor(mt, 32));
    float mn = fmaxf(m_run, mt);
    float corr = __expf(m_run - mn);
    m_run = mn;
    f32x4 pe[4];
    float ps = 0.f;
    #pragma unroll
    for (int nt = 0; nt < 4; ++nt)
      #pragma unroll
      for (int j = 0; j < 4; ++j){ float p = __expf(sa[nt][j] - mn); pe[nt][j] = p; ps += p; }
    ps += __shfl_xor(ps, 16);
    ps += __shfl_xor(ps, 32);
    l_run = l_run * corr + ps;
    #pragma unroll
    for (int dt = 0; dt < 4; ++dt)
      #pragma unroll
      for (int j = 0; j < 4; ++j) o[dt][j] *= corr;

    // pack P to bf16 pairs and redistribute to PV B-fragment layout
    unsigned pr[8];
    #pragma unroll
    for (int nt = 0; nt < 4; ++nt)
      #pragma unroll
      for (int h2 = 0; h2 < 2; ++h2) pr[nt * 2 + h2] = pack2(pe[nt][2 * h2], pe[nt][2 * h2 + 1]);
    short8 breg[2];
    #pragma unroll
    for (int ks = 0; ks < 2; ++ks){
      union { unsigned u[4]; short8 s; } bb;
      #pragma unroll
      for (int r = 0; r < 4; ++r){
        int srcl = l15 + ((g & 1) << 5) + ((r >> 1) << 4);
        unsigned va = __shfl(pr[4 * ks + (r & 1)], srcl);
        unsigned vb = __shfl(pr[4 * ks + 2 + (r & 1)], srcl);
        bb.u[r] = (g >> 1) ? vb : va;
      }
      breg[ks] = bb.s;
    }

    // PV swapped: O^T[d][q] += mfma(V^T-frag, P^T-frag)
    __builtin_amdgcn_s_setprio(1);
    #pragma unroll
    for (int dt = 0; dt < 4; ++dt){
      int rr = dt * 16 + l15;
      short8 v0 = *(const short8*)(vsb + rr * 64 + ((g ^ rx) << 3));
      short8 v1 = *(const short8*)(vsb + rr * 64 + (((4 + g) ^ rx) << 3));
      o[dt] = __builtin_amdgcn_mfma_f32_16x16x32_bf16(v0, breg[0], o[dt], 0, 0, 0);
      o[dt] = __builtin_amdgcn_mfma_f32_16x16x32_bf16(v1, breg[1], o[dt], 0, 0, 0);
    }
    __builtin_amdgcn_s_setprio(0);
    SB0();
    __builtin_amdgcn_s_barrier();
  }
#undef STAGE

  float inv = 1.f / l_run;
  int b = bh >> 3, h = bh & 7;
  size_t obase = ((size_t)b * NQ + q0 + l15) * 512 + h * 64 + g * 4;
  #pragma unroll
  for (int dt = 0; dt < 4; ++dt){
    ushort4 pk;
    pk.x = f2bf(o[dt][0] * inv); pk.y = f2bf(o[dt][1] * inv);
    pk.z = f2bf(o[dt][2] * inv); pk.w = f2bf(o[dt][3] * inv);
    *(ushort4*)(net + obase + dt * 16) = pk;
  }
}

extern "C" void kernel_launch(void* const* d_in, const int* in_sizes, int n_in,
                              void* d_out, int out_size, void* d_ws, size_t ws_size,
                              hipStream_t stream){
  const float* x      = (const float*)d_in[0];
  const float* q_w    = (const float*)d_in[1];
  const float* kv_w   = (const float*)d_in[2];
  const float* proj_w = (const float*)d_in[3];
  const float* proj_b = (const float*)d_in[4];
  const float* sr_w   = (const float*)d_in[5];
  const float* sr_b   = (const float*)d_in[6];
  const float* ln_w   = (const float*)d_in[7];
  const float* ln_b   = (const float*)d_in[8];
  (void)in_sizes; (void)n_in; (void)out_size; (void)ws_size;

  char* ws = (char*)d_ws;
  u16*   x_bf    = (u16*)(ws);                               // 16 MB
  u16*   a_conv  = (u16*)(ws + ((size_t)16 << 20));          // 16 MB (reused by net)
  u16*   net     = (u16*)(ws + ((size_t)16 << 20));
  u16*   q_sb    = (u16*)(ws + ((size_t)32 << 20));          // 16 MB
  float* xr_pre  = (float*)(ws + ((size_t)48 << 20));        // 8 MB (reused by k/v)
  u16*   k_sb    = (u16*)(ws + ((size_t)48 << 20));          // 4 MB
  u16*   vt_sb   = (u16*)(ws + ((size_t)52 << 20));          // 4 MB (V^T [bh][d][p])
  u16*   xr      = (u16*)(ws + ((size_t)56 << 20));          // 4 MB
  u16*   q_wT    = (u16*)(ws + ((size_t)60 << 20));
  u16*   kv_wT   = (u16*)(ws + ((size_t)60 << 20) + 524288);
  u16*   proj_wT = (u16*)(ws + ((size_t)60 << 20) + 524288 + 1048576);
  u16*   conv_BT = (u16*)(ws + ((size_t)60 << 20) + 524288 + 1048576 + 524288);
  float* out = (float*)d_out;

  prep_w<<<8192, 256, 0, stream>>>(q_w, kv_w, proj_w, sr_w, q_wT, kv_wT, proj_wT, conv_BT);
  prep_x<<<4096, 256, 0, stream>>>(x, x_bf, a_conv);
  gemm_bt<1><<<dim3(4, 128), 256, 0, stream>>>(x_bf, q_wT, nullptr, q_sb, nullptr, nullptr, 16384, 512, 512);
  gemm_bt<0><<<dim3(4, 32),  256, 0, stream>>>(a_conv, conv_BT, xr_pre, nullptr, nullptr, sr_b, 4096, 512, 2048);
  ln_k<<<1024, 256, 0, stream>>>(xr_pre, ln_w, ln_b, xr);
  gemm_bt<2><<<dim3(8, 32),  256, 0, stream>>>(xr, kv_wT, nullptr, k_sb, vt_sb, nullptr, 4096, 1024, 512);
  attn_k<<<dim3(64, 32), 256, 0, stream>>>(q_sb, k_sb, vt_sb, net);
  gemm_bt<0><<<dim3(4, 128), 256, 0, stream>>>(net, proj_wT, out, nullptr, nullptr, proj_b, 16384, 512, 512);
}

// Round 4
// 177.726 us; speedup vs baseline: 1.6332x; 1.1650x over previous
//
#include <hip/hip_runtime.h>
#include <cstdint>

#define HEADS 8
#define HD 64
#define NQ 4096
#define NKV 1024

typedef unsigned short u16;
typedef __attribute__((ext_vector_type(8))) short short8;
typedef __attribute__((ext_vector_type(4))) float f32x4;

__device__ __forceinline__ u16 f2bf(float f){
  union { float f; unsigned u; } c; c.f = f;
  unsigned r = c.u + 0x7fffu + ((c.u >> 16) & 1u);
  return (u16)(r >> 16);
}
__device__ __forceinline__ unsigned pack2(float a, float b){
  return (unsigned)f2bf(a) | ((unsigned)f2bf(b) << 16);
}
__device__ __forceinline__ float fexp2(float x){
  float r;
  asm("v_exp_f32 %0, %1" : "=v"(r) : "v"(x));
  return r;
}
__device__ __forceinline__ unsigned cvtpk(float a, float b){
  unsigned r;
  asm("v_cvt_pk_bf16_f32 %0, %1, %2" : "=v"(r) : "v"(a), "v"(b));
  return r;
}
__device__ __forceinline__ void gll16(const void* g, void* l){
  __builtin_amdgcn_global_load_lds((const __attribute__((address_space(1))) unsigned*)g,
                                   (__attribute__((address_space(3))) unsigned*)l, 16, 0, 0);
}
#define SB0() __builtin_amdgcn_sched_barrier(0)

// ---- prep: x -> bf16 (both token layout and conv-patch layout) ----
__global__ __launch_bounds__(256) void prep_x(const float* __restrict__ x,
                                              u16* __restrict__ x_bf,
                                              u16* __restrict__ a_conv){
  int tid = blockIdx.x * 256 + threadIdx.x;
  int b   = tid >> 18;
  int rem = tid & 262143;
  int pos = rem >> 6;
  int ci0 = (rem & 63) << 3;
  size_t src = ((size_t)(b * NQ + pos)) * 512 + ci0;
  const float4* s4 = (const float4*)(x + src);
  float4 v0 = s4[0], v1 = s4[1];
  uint4 p;
  p.x = pack2(v0.x, v0.y); p.y = pack2(v0.z, v0.w);
  p.z = pack2(v1.x, v1.y); p.w = pack2(v1.z, v1.w);
  *(uint4*)(x_bf + src) = p;
  int h = pos >> 6, w = pos & 63;
  int pr = (h >> 1) * 32 + (w >> 1);
  int t  = (h & 1) * 2 + (w & 1);
  *(uint4*)(a_conv + ((size_t)(b * NKV + pr)) * 2048 + t * 512 + ci0) = p;
}

// ---- prep: weights -> bf16, transposed to [N][K] ----
__global__ __launch_bounds__(256) void prep_w(const float* __restrict__ q_w,
                                              const float* __restrict__ kv_w,
                                              const float* __restrict__ proj_w,
                                              const float* __restrict__ sr_w,
                                              u16* __restrict__ q_wT, u16* __restrict__ kv_wT,
                                              u16* __restrict__ proj_wT, u16* __restrict__ conv_BT){
  int e = blockIdx.x * 256 + threadIdx.x;
  if (e < 262144){ int n = e >> 9, k = e & 511; q_wT[e] = f2bf(q_w[k * 512 + n]); return; }
  e -= 262144;
  if (e < 524288){ int n = e >> 9, k = e & 511; kv_wT[e] = f2bf(kv_w[k * 1024 + n]); return; }
  e -= 524288;
  if (e < 262144){ int n = e >> 9, k = e & 511; proj_wT[e] = f2bf(proj_w[k * 512 + n]); return; }
  e -= 262144;
  { int co = e >> 11, r = e & 2047, t = r >> 9, ci = r & 511;
    conv_BT[e] = f2bf(sr_w[co * 2048 + ci * 4 + t]); }
}

// ---- GEMM: C[M,N] = A[M,K] @ BT[N,K]^T,  128x128 tile, BK=32, 4 waves ----
// Split-K via gridDim.z (MODE 0 writes per-z partial buffers; bias only z==0).
// MODE 0: fp32 out (+bias).  MODE 1: q scatter (bf16, *0.125*log2e).  MODE 2: k + v^T scatter.
template<int MODE>
__global__ __launch_bounds__(256) void gemm_bt(const u16* __restrict__ A, const u16* __restrict__ BT,
                                               float* __restrict__ Cf, u16* __restrict__ Cb0,
                                               u16* __restrict__ Cb1, const float* __restrict__ bias,
                                               int M, int N, int K){
  __shared__ __align__(16) u16 As[128 * 32];
  __shared__ __align__(16) u16 Bs[128 * 32];
  const int tid = threadIdx.x, lane = tid & 63, wave = tid >> 6;
  const int m0 = blockIdx.y * 128, n0 = blockIdx.x * 128;
  const int wr = wave >> 1, wc = wave & 1;
  const int kz = blockIdx.z;
  const int klen = K / (int)gridDim.z;
  const int kb = kz * klen;
  f32x4 acc[4][4] = {};
  for (int kt = kb; kt < kb + klen; kt += 32){
    #pragma unroll
    for (int i = 0; i < 2; ++i){
      int c = i * 256 + tid;
      int row = c >> 2, ks = (c & 3) << 3;
      gll16(A  + (size_t)(m0 + row) * K + kt + ks, As + (size_t)(i * 256 + wave * 64) * 8);
      gll16(BT + (size_t)(n0 + row) * K + kt + ks, Bs + (size_t)(i * 256 + wave * 64) * 8);
    }
    __syncthreads();
    short8 af[4];
    #pragma unroll
    for (int mi = 0; mi < 4; ++mi)
      af[mi] = *(const short8*)(As + (wr * 64 + mi * 16 + (lane & 15)) * 32 + (lane >> 4) * 8);
    #pragma unroll
    for (int ni = 0; ni < 4; ++ni){
      short8 bf = *(const short8*)(Bs + (wc * 64 + ni * 16 + (lane & 15)) * 32 + (lane >> 4) * 8);
      #pragma unroll
      for (int mi = 0; mi < 4; ++mi)
        acc[mi][ni] = __builtin_amdgcn_mfma_f32_16x16x32_bf16(af[mi], bf, acc[mi][ni], 0, 0, 0);
    }
    __syncthreads();
  }
  #pragma unroll
  for (int mi = 0; mi < 4; ++mi){
    int row = m0 + wr * 64 + mi * 16 + (lane >> 4) * 4;
    #pragma unroll
    for (int ni = 0; ni < 4; ++ni){
      int col = n0 + wc * 64 + ni * 16 + (lane & 15);
      f32x4 v = acc[mi][ni];
      if (MODE == 0){
        float* Co = Cf + (size_t)kz * M * N;
        float bb = (bias && kz == 0) ? bias[col] : 0.f;
        #pragma unroll
        for (int j = 0; j < 4; ++j) Co[(size_t)(row + j) * N + col] = v[j] + bb;
      } else if (MODE == 1){
        int h = col >> 6, d = col & 63;
        #pragma unroll
        for (int j = 0; j < 4; ++j){
          int r = row + j, b = r >> 12, nq = r & 4095;
          Cb0[(((size_t)(b * HEADS + h)) * NQ + nq) * HD + d] = f2bf(v[j] * 0.18033688f);
        }
      } else {
        int s = col >> 9, h = (col >> 6) & 7, d = col & 63;
        if (s == 0){
          #pragma unroll
          for (int j = 0; j < 4; ++j){
            int r = row + j, b = r >> 10, p = r & 1023;
            Cb0[(((size_t)(b * HEADS + h)) * NKV + p) * HD + d] = f2bf(v[j]);
          }
        } else {                               // V^T: [bh][d][p], 4 consecutive p packed
          int b = row >> 10, p0 = row & 1023;
          ushort4 pk;
          pk.x = f2bf(v[0]); pk.y = f2bf(v[1]); pk.z = f2bf(v[2]); pk.w = f2bf(v[3]);
          *(ushort4*)(Cb1 + (((size_t)(b * HEADS + h)) * HD + d) * NKV + p0) = pk;
        }
      }
    }
  }
}

// ---- LayerNorm over 512 cols; sums two split-K partials; fp32 in, bf16 out ----
__global__ __launch_bounds__(256) void ln_k(const float* __restrict__ xp, const float* __restrict__ w,
                                            const float* __restrict__ bias, u16* __restrict__ xr){
  int row = blockIdx.x * 4 + (threadIdx.x >> 6);
  int lane = threadIdx.x & 63;
  const float* src  = xp + (size_t)row * 512;
  const float* src2 = src + (size_t)4096 * 512;
  float vals[8]; float s = 0.f, ss = 0.f;
  #pragma unroll
  for (int j = 0; j < 8; ++j){
    float v = src[lane + j * 64] + src2[lane + j * 64];
    vals[j] = v; s += v; ss += v * v;
  }
  #pragma unroll
  for (int off = 32; off >= 1; off >>= 1){ s += __shfl_xor(s, off); ss += __shfl_xor(ss, off); }
  float mean = s * (1.f / 512.f);
  float var  = ss * (1.f / 512.f) - mean * mean;
  float rs = rsqrtf(var + 1e-5f);
  u16* dst = xr + (size_t)row * 512;
  #pragma unroll
  for (int j = 0; j < 8; ++j){
    int c = lane + j * 64;
    dst[c] = f2bf((vals[j] - mean) * rs * w[c] + bias[c]);
  }
}

// ---- flash attention v3: swapped QK^T, no-max exp2 softmax, l via ones-MFMA ----
// q pre-scaled by (1/8)*log2(e) so p = 2^s.
template<bool LAST>
__device__ __forceinline__ void attn_tile(const u16* ksb, const u16* vsb,
                                          u16* kstage, u16* vstage,
                                          const u16* akg, const u16* avg,
                                          short8 qf0, short8 qf1, short8 ones,
                                          int l15, int g, int rx,
                                          f32x4* o, f32x4& ol){
  SB0();
  if (!LAST){
    gll16(akg,              kstage);
    gll16(akg + 2048,       kstage + 2048);
    gll16(avg,              vstage);
    gll16(avg + 32 * 1024,  vstage + 2048);
    SB0();
    asm volatile("s_waitcnt vmcnt(4)" ::: "memory");
  } else {
    asm volatile("s_waitcnt vmcnt(0)" ::: "memory");
  }
  __builtin_amdgcn_s_barrier();
  SB0();

  // QK^T swapped: S^T[kv][q] = mfma(K-frag, Q-frag)
  f32x4 sa[4];
  __builtin_amdgcn_s_setprio(1);
  #pragma unroll
  for (int nt = 0; nt < 4; ++nt){
    int r = nt * 16 + l15;
    short8 k0 = *(const short8*)(ksb + r * 64 + ((g ^ rx) << 3));
    short8 k1 = *(const short8*)(ksb + r * 64 + (((4 + g) ^ rx) << 3));
    f32x4 a = {0.f, 0.f, 0.f, 0.f};
    a = __builtin_amdgcn_mfma_f32_16x16x32_bf16(k0, qf0, a, 0, 0, 0);
    a = __builtin_amdgcn_mfma_f32_16x16x32_bf16(k1, qf1, a, 0, 0, 0);
    sa[nt] = a;
  }
  __builtin_amdgcn_s_setprio(0);

  // prefetch V fragments (latency hides under softmax)
  short8 vf0[4], vf1[4];
  #pragma unroll
  for (int dt = 0; dt < 4; ++dt){
    int rr = dt * 16 + l15;
    vf0[dt] = *(const short8*)(vsb + rr * 64 + ((g ^ rx) << 3));
    vf1[dt] = *(const short8*)(vsb + rr * 64 + (((4 + g) ^ rx) << 3));
  }

  // softmax-lite: p = 2^s, packed to bf16 pairs
  unsigned pr[8];
  #pragma unroll
  for (int nt = 0; nt < 4; ++nt){
    float p0 = fexp2(sa[nt][0]), p1 = fexp2(sa[nt][1]);
    float p2 = fexp2(sa[nt][2]), p3 = fexp2(sa[nt][3]);
    pr[nt * 2]     = cvtpk(p0, p1);
    pr[nt * 2 + 1] = cvtpk(p2, p3);
  }
  // redistribute to PV B-fragment layout
  short8 breg[2];
  #pragma unroll
  for (int ks = 0; ks < 2; ++ks){
    union { unsigned u[4]; short8 s; } bb;
    #pragma unroll
    for (int r = 0; r < 4; ++r){
      int srcl = l15 + ((g & 1) << 5) + ((r >> 1) << 4);
      unsigned va = __shfl(pr[4 * ks + (r & 1)], srcl);
      unsigned vb = __shfl(pr[4 * ks + 2 + (r & 1)], srcl);
      bb.u[r] = (g >> 1) ? vb : va;
    }
    breg[ks] = bb.s;
  }

  // PV swapped + l via ones-MFMA
  __builtin_amdgcn_s_setprio(1);
  #pragma unroll
  for (int dt = 0; dt < 4; ++dt){
    o[dt] = __builtin_amdgcn_mfma_f32_16x16x32_bf16(vf0[dt], breg[0], o[dt], 0, 0, 0);
    o[dt] = __builtin_amdgcn_mfma_f32_16x16x32_bf16(vf1[dt], breg[1], o[dt], 0, 0, 0);
  }
  ol = __builtin_amdgcn_mfma_f32_16x16x32_bf16(ones, breg[0], ol, 0, 0, 0);
  ol = __builtin_amdgcn_mfma_f32_16x16x32_bf16(ones, breg[1], ol, 0, 0, 0);
  __builtin_amdgcn_s_setprio(0);
  SB0();
  __builtin_amdgcn_s_barrier();
}

__global__ __launch_bounds__(256) void attn_k(const u16* __restrict__ q_s, const u16* __restrict__ k_s,
                                              const u16* __restrict__ vt_s, u16* __restrict__ net){
  __shared__ __align__(16) u16 Ks[2][64 * 64];
  __shared__ __align__(16) u16 Vt[2][64 * 64];
  const int tid = threadIdx.x, lane = tid & 63, wave = tid >> 6;
  const int l15 = lane & 15, g = lane >> 4, rx = l15 & 7;
  const int bh = blockIdx.y;
  const u16* kb  = k_s  + (size_t)bh * NKV * HD;
  const u16* vtb = vt_s + (size_t)bh * HD * NKV;
  const int q0 = blockIdx.x * 64 + wave * 16;
  const u16* qrow = q_s + ((size_t)bh * NQ + q0 + l15) * HD + g * 8;
  short8 qf0 = *(const short8*)(qrow);
  short8 qf1 = *(const short8*)(qrow + 32);
  const short8 ones = {0x3F80, 0x3F80, 0x3F80, 0x3F80, 0x3F80, 0x3F80, 0x3F80, 0x3F80};

  // per-lane pre-swizzled global staging addresses (chunk ^= row&7; LDS stays linear)
  const int swz8 = (((tid & 7) ^ ((tid >> 3) & 7)) << 3);
  const u16* ak0 = kb  + (size_t)(tid >> 3) * 64   + swz8;
  const u16* av0 = vtb + (size_t)(tid >> 3) * 1024 + swz8;

  f32x4 o[4] = {};
  f32x4 ol = {};

  // prologue: stage tile 0 into buf 0
  gll16(ak0,             &Ks[0][wave * 512]);
  gll16(ak0 + 2048,      &Ks[0][2048 + wave * 512]);
  gll16(av0,             &Vt[0][wave * 512]);
  gll16(av0 + 32 * 1024, &Vt[0][2048 + wave * 512]);

  for (int tt = 0; tt < 7; ++tt){
    attn_tile<false>(&Ks[0][0], &Vt[0][0], &Ks[1][wave * 512], &Vt[1][wave * 512],
                     ak0 + (size_t)(2 * tt + 1) * 4096, av0 + (2 * tt + 1) * 64,
                     qf0, qf1, ones, l15, g, rx, o, ol);
    attn_tile<false>(&Ks[1][0], &Vt[1][0], &Ks[0][wave * 512], &Vt[0][wave * 512],
                     ak0 + (size_t)(2 * tt + 2) * 4096, av0 + (2 * tt + 2) * 64,
                     qf0, qf1, ones, l15, g, rx, o, ol);
  }
  attn_tile<false>(&Ks[0][0], &Vt[0][0], &Ks[1][wave * 512], &Vt[1][wave * 512],
                   ak0 + (size_t)15 * 4096, av0 + 15 * 64,
                   qf0, qf1, ones, l15, g, rx, o, ol);
  attn_tile<true>(&Ks[1][0], &Vt[1][0], nullptr, nullptr, nullptr, nullptr,
                  qf0, qf1, ones, l15, g, rx, o, ol);

  float inv = 1.f / ol[0];
  int b = bh >> 3, h = bh & 7;
  size_t obase = ((size_t)b * NQ + q0 + l15) * 512 + h * 64 + g * 4;
  #pragma unroll
  for (int dt = 0; dt < 4; ++dt){
    uint2 pk;
    pk.x = cvtpk(o[dt][0] * inv, o[dt][1] * inv);
    pk.y = cvtpk(o[dt][2] * inv, o[dt][3] * inv);
    *(uint2*)(net + obase + dt * 16) = pk;
  }
}

extern "C" void kernel_launch(void* const* d_in, const int* in_sizes, int n_in,
                              void* d_out, int out_size, void* d_ws, size_t ws_size,
                              hipStream_t stream){
  const float* x      = (const float*)d_in[0];
  const float* q_w    = (const float*)d_in[1];
  const float* kv_w   = (const float*)d_in[2];
  const float* proj_w = (const float*)d_in[3];
  const float* proj_b = (const float*)d_in[4];
  const float* sr_w   = (const float*)d_in[5];
  const float* sr_b   = (const float*)d_in[6];
  const float* ln_w   = (const float*)d_in[7];
  const float* ln_b   = (const float*)d_in[8];
  (void)in_sizes; (void)n_in; (void)out_size; (void)ws_size;

  char* ws = (char*)d_ws;
  u16*   x_bf    = (u16*)(ws);                               // 0..16 MB
  u16*   a_conv  = (u16*)(ws + ((size_t)16 << 20));          // 16..32 MB (dead after conv)
  u16*   xr      = (u16*)(ws + ((size_t)16 << 20));          // 16..20 MB (dead after kv gemm)
  u16*   net     = (u16*)(ws + ((size_t)16 << 20));          // 16..32 MB (attn output)
  u16*   q_sb    = (u16*)(ws + ((size_t)32 << 20));          // 32..48 MB
  float* xr_pre  = (float*)(ws + ((size_t)48 << 20));        // 48..64 MB (2 split-K halves)
  u16*   k_sb    = (u16*)(ws + ((size_t)48 << 20));          // 48..52 MB (after ln)
  u16*   vt_sb   = (u16*)(ws + ((size_t)52 << 20));          // 52..56 MB (V^T [bh][d][p])
  u16*   q_wT    = (u16*)(ws + ((size_t)64 << 20));
  u16*   kv_wT   = (u16*)(ws + ((size_t)64 << 20) + 524288);
  u16*   proj_wT = (u16*)(ws + ((size_t)64 << 20) + 524288 + 1048576);
  u16*   conv_BT = (u16*)(ws + ((size_t)64 << 20) + 524288 + 1048576 + 524288);
  float* out = (float*)d_out;

  prep_w<<<8192, 256, 0, stream>>>(q_w, kv_w, proj_w, sr_w, q_wT, kv_wT, proj_wT, conv_BT);
  prep_x<<<4096, 256, 0, stream>>>(x, x_bf, a_conv);
  gemm_bt<1><<<dim3(4, 128), 256, 0, stream>>>(x_bf, q_wT, nullptr, q_sb, nullptr, nullptr, 16384, 512, 512);
  gemm_bt<0><<<dim3(4, 32, 2), 256, 0, stream>>>(a_conv, conv_BT, xr_pre, nullptr, nullptr, sr_b, 4096, 512, 2048);
  ln_k<<<1024, 256, 0, stream>>>(xr_pre, ln_w, ln_b, xr);
  gemm_bt<2><<<dim3(8, 32),  256, 0, stream>>>(xr, kv_wT, nullptr, k_sb, vt_sb, nullptr, 4096, 1024, 512);
  attn_k<<<dim3(64, 32), 256, 0, stream>>>(q_sb, k_sb, vt_sb, net);
  gemm_bt<0><<<dim3(4, 128), 256, 0, stream>>>(net, proj_wT, out, nullptr, nullptr, proj_b, 16384, 512, 512);
}

// Round 5
// 170.073 us; speedup vs baseline: 1.7066x; 1.0450x over previous
//
#include <hip/hip_runtime.h>
#include <cstdint>

#define HEADS 8
#define HD 64
#define NQ 4096
#define NKV 1024

typedef unsigned short u16;
typedef __attribute__((ext_vector_type(8))) short short8;
typedef __attribute__((ext_vector_type(4))) float f32x4;

__device__ __forceinline__ u16 f2bf(float f){
  union { float f; unsigned u; } c; c.f = f;
  unsigned r = c.u + 0x7fffu + ((c.u >> 16) & 1u);
  return (u16)(r >> 16);
}
__device__ __forceinline__ unsigned pack2(float a, float b){
  return (unsigned)f2bf(a) | ((unsigned)f2bf(b) << 16);
}
__device__ __forceinline__ float fexp2(float x){
  float r;
  asm("v_exp_f32 %0, %1" : "=v"(r) : "v"(x));
  return r;
}
__device__ __forceinline__ unsigned cvtpk(float a, float b){
  unsigned r;
  asm("v_cvt_pk_bf16_f32 %0, %1, %2" : "=v"(r) : "v"(a), "v"(b));
  return r;
}
__device__ __forceinline__ void gll16(const void* g, void* l){
  __builtin_amdgcn_global_load_lds((const __attribute__((address_space(1))) unsigned*)g,
                                   (__attribute__((address_space(3))) unsigned*)l, 16, 0, 0);
}
#define SB0() __builtin_amdgcn_sched_barrier(0)
#define MFMA16(a, b, c) __builtin_amdgcn_mfma_f32_16x16x32_bf16(a, b, c, 0, 0, 0)

// ---- prep: x -> bf16 (both token layout and conv-patch layout) ----
__global__ __launch_bounds__(256) void prep_x(const float* __restrict__ x,
                                              u16* __restrict__ x_bf,
                                              u16* __restrict__ a_conv){
  int tid = blockIdx.x * 256 + threadIdx.x;
  int b   = tid >> 18;
  int rem = tid & 262143;
  int pos = rem >> 6;
  int ci0 = (rem & 63) << 3;
  size_t src = ((size_t)(b * NQ + pos)) * 512 + ci0;
  const float4* s4 = (const float4*)(x + src);
  float4 v0 = s4[0], v1 = s4[1];
  uint4 p;
  p.x = pack2(v0.x, v0.y); p.y = pack2(v0.z, v0.w);
  p.z = pack2(v1.x, v1.y); p.w = pack2(v1.z, v1.w);
  *(uint4*)(x_bf + src) = p;
  int h = pos >> 6, w = pos & 63;
  int pr = (h >> 1) * 32 + (w >> 1);
  int t  = (h & 1) * 2 + (w & 1);
  *(uint4*)(a_conv + ((size_t)(b * NKV + pr)) * 2048 + t * 512 + ci0) = p;
}

// ---- prep: weights -> bf16, transposed to [N][K] ----
__global__ __launch_bounds__(256) void prep_w(const float* __restrict__ q_w,
                                              const float* __restrict__ kv_w,
                                              const float* __restrict__ proj_w,
                                              const float* __restrict__ sr_w,
                                              u16* __restrict__ q_wT, u16* __restrict__ kv_wT,
                                              u16* __restrict__ proj_wT, u16* __restrict__ conv_BT){
  int e = blockIdx.x * 256 + threadIdx.x;
  if (e < 262144){ int n = e >> 9, k = e & 511; q_wT[e] = f2bf(q_w[k * 512 + n]); return; }
  e -= 262144;
  if (e < 524288){ int n = e >> 9, k = e & 511; kv_wT[e] = f2bf(kv_w[k * 1024 + n]); return; }
  e -= 524288;
  if (e < 262144){ int n = e >> 9, k = e & 511; proj_wT[e] = f2bf(proj_w[k * 512 + n]); return; }
  e -= 262144;
  { int co = e >> 11, r = e & 2047, t = r >> 9, ci = r & 511;
    conv_BT[e] = f2bf(sr_w[co * 2048 + ci * 4 + t]); }
}

// ---- GEMM: C[M,N] = A[M,K] @ BT[N,K]^T,  128x128 tile, BK=32, 4 waves ----
// Split-K via gridDim.z; z partials 0,1 -> Cf, partials 2,3 -> Cf2; bias only z==0.
// MODE 0: fp32 out (+bias).  MODE 1: q scatter (bf16, *0.125*log2e).  MODE 2: k + v^T scatter.
template<int MODE>
__global__ __launch_bounds__(256) void gemm_bt(const u16* __restrict__ A, const u16* __restrict__ BT,
                                               float* __restrict__ Cf, float* __restrict__ Cf2,
                                               u16* __restrict__ Cb0,
                                               u16* __restrict__ Cb1, const float* __restrict__ bias,
                                               int M, int N, int K){
  __shared__ __align__(16) u16 As[128 * 32];
  __shared__ __align__(16) u16 Bs[128 * 32];
  const int tid = threadIdx.x, lane = tid & 63, wave = tid >> 6;
  const int m0 = blockIdx.y * 128, n0 = blockIdx.x * 128;
  const int wr = wave >> 1, wc = wave & 1;
  const int kz = blockIdx.z;
  const int klen = K / (int)gridDim.z;
  const int kb = kz * klen;
  f32x4 acc[4][4] = {};
  for (int kt = kb; kt < kb + klen; kt += 32){
    #pragma unroll
    for (int i = 0; i < 2; ++i){
      int c = i * 256 + tid;
      int row = c >> 2, ks = (c & 3) << 3;
      gll16(A  + (size_t)(m0 + row) * K + kt + ks, As + (size_t)(i * 256 + wave * 64) * 8);
      gll16(BT + (size_t)(n0 + row) * K + kt + ks, Bs + (size_t)(i * 256 + wave * 64) * 8);
    }
    __syncthreads();
    short8 af[4];
    #pragma unroll
    for (int mi = 0; mi < 4; ++mi)
      af[mi] = *(const short8*)(As + (wr * 64 + mi * 16 + (lane & 15)) * 32 + (lane >> 4) * 8);
    #pragma unroll
    for (int ni = 0; ni < 4; ++ni){
      short8 bf = *(const short8*)(Bs + (wc * 64 + ni * 16 + (lane & 15)) * 32 + (lane >> 4) * 8);
      #pragma unroll
      for (int mi = 0; mi < 4; ++mi)
        acc[mi][ni] = MFMA16(af[mi], bf, acc[mi][ni]);
    }
    __syncthreads();
  }
  #pragma unroll
  for (int mi = 0; mi < 4; ++mi){
    int row = m0 + wr * 64 + mi * 16 + (lane >> 4) * 4;
    #pragma unroll
    for (int ni = 0; ni < 4; ++ni){
      int col = n0 + wc * 64 + ni * 16 + (lane & 15);
      f32x4 v = acc[mi][ni];
      if (MODE == 0){
        float* Co = (kz < 2) ? (Cf + (size_t)kz * M * N) : (Cf2 + (size_t)(kz - 2) * M * N);
        float bb = (bias && kz == 0) ? bias[col] : 0.f;
        #pragma unroll
        for (int j = 0; j < 4; ++j) Co[(size_t)(row + j) * N + col] = v[j] + bb;
      } else if (MODE == 1){
        int h = col >> 6, d = col & 63;
        #pragma unroll
        for (int j = 0; j < 4; ++j){
          int r = row + j, b = r >> 12, nq = r & 4095;
          Cb0[(((size_t)(b * HEADS + h)) * NQ + nq) * HD + d] = f2bf(v[j] * 0.18033688f);
        }
      } else {
        int s = col >> 9, h = (col >> 6) & 7, d = col & 63;
        if (s == 0){
          #pragma unroll
          for (int j = 0; j < 4; ++j){
            int r = row + j, b = r >> 10, p = r & 1023;
            Cb0[(((size_t)(b * HEADS + h)) * NKV + p) * HD + d] = f2bf(v[j]);
          }
        } else {                               // V^T: [bh][d][p], 4 consecutive p packed
          int b = row >> 10, p0 = row & 1023;
          ushort4 pk;
          pk.x = f2bf(v[0]); pk.y = f2bf(v[1]); pk.z = f2bf(v[2]); pk.w = f2bf(v[3]);
          *(ushort4*)(Cb1 + (((size_t)(b * HEADS + h)) * HD + d) * NKV + p0) = pk;
        }
      }
    }
  }
}

// ---- LayerNorm over 512 cols; sums four split-K partials; fp32 in, bf16 out ----
__global__ __launch_bounds__(256) void ln_k(const float* __restrict__ xp, const float* __restrict__ xp2,
                                            const float* __restrict__ w,
                                            const float* __restrict__ bias, u16* __restrict__ xr){
  int row = blockIdx.x * 4 + (threadIdx.x >> 6);
  int lane = threadIdx.x & 63;
  const float* s1 = xp  + (size_t)row * 512;
  const float* s2 = s1 + (size_t)4096 * 512;
  const float* s3 = xp2 + (size_t)row * 512;
  const float* s4 = s3 + (size_t)4096 * 512;
  float vals[8]; float s = 0.f, ss = 0.f;
  #pragma unroll
  for (int j = 0; j < 8; ++j){
    int c = lane + j * 64;
    float v = (s1[c] + s2[c]) + (s3[c] + s4[c]);
    vals[j] = v; s += v; ss += v * v;
  }
  #pragma unroll
  for (int off = 32; off >= 1; off >>= 1){ s += __shfl_xor(s, off); ss += __shfl_xor(ss, off); }
  float mean = s * (1.f / 512.f);
  float var  = ss * (1.f / 512.f) - mean * mean;
  float rs = rsqrtf(var + 1e-5f);
  u16* dst = xr + (size_t)row * 512;
  #pragma unroll
  for (int j = 0; j < 8; ++j){
    int c = lane + j * 64;
    dst[c] = f2bf((vals[j] - mean) * rs * w[c] + bias[c]);
  }
}

// ---- flash attention v4: 2 q-sets per wave (32 rows), shared K/V tiles & frags ----
// q pre-scaled by (1/8)*log2(e) so p = 2^s; no-max softmax; l via ones-MFMA.
template<bool LAST>
__device__ __forceinline__ void attn_tile(const u16* ksb, const u16* vsb,
                                          u16* kstage, u16* vstage,
                                          const u16* akg, const u16* avg,
                                          const short8* qf, short8 ones,
                                          int l15, int g, int rx,
                                          f32x4* oA, f32x4* oB, f32x4& olA, f32x4& olB){
  SB0();
  if (!LAST){
    gll16(akg,              kstage);
    gll16(akg + 2048,       kstage + 2048);
    gll16(avg,              vstage);
    gll16(avg + 32 * 1024,  vstage + 2048);
    SB0();
    asm volatile("s_waitcnt vmcnt(4)" ::: "memory");
  } else {
    asm volatile("s_waitcnt vmcnt(0)" ::: "memory");
  }
  __builtin_amdgcn_s_barrier();
  SB0();

  // QK^T swapped for both q-sets; exp2 + pack immediately per nt (short sa life)
  unsigned prA[8], prB[8];
  __builtin_amdgcn_s_setprio(1);
  #pragma unroll
  for (int nt = 0; nt < 4; ++nt){
    int r = nt * 16 + l15;
    short8 k0 = *(const short8*)(ksb + r * 64 + ((g ^ rx) << 3));
    short8 k1 = *(const short8*)(ksb + r * 64 + (((4 + g) ^ rx) << 3));
    f32x4 aA = {0.f, 0.f, 0.f, 0.f}, aB = {0.f, 0.f, 0.f, 0.f};
    aA = MFMA16(k0, qf[0], aA);
    aA = MFMA16(k1, qf[1], aA);
    aB = MFMA16(k0, qf[2], aB);
    aB = MFMA16(k1, qf[3], aB);
    prA[nt * 2]     = cvtpk(fexp2(aA[0]), fexp2(aA[1]));
    prA[nt * 2 + 1] = cvtpk(fexp2(aA[2]), fexp2(aA[3]));
    prB[nt * 2]     = cvtpk(fexp2(aB[0]), fexp2(aB[1]));
    prB[nt * 2 + 1] = cvtpk(fexp2(aB[2]), fexp2(aB[3]));
  }
  __builtin_amdgcn_s_setprio(0);

  // redistribute to PV B-fragment layout
  short8 bregA[2], bregB[2];
  #pragma unroll
  for (int ks = 0; ks < 2; ++ks){
    union { unsigned u[4]; short8 s; } bA, bB;
    #pragma unroll
    for (int r = 0; r < 4; ++r){
      int srcl = l15 + ((g & 1) << 5) + ((r >> 1) << 4);
      unsigned vaA = __shfl(prA[4 * ks + (r & 1)], srcl);
      unsigned vbA = __shfl(prA[4 * ks + 2 + (r & 1)], srcl);
      bA.u[r] = (g >> 1) ? vbA : vaA;
      unsigned vaB = __shfl(prB[4 * ks + (r & 1)], srcl);
      unsigned vbB = __shfl(prB[4 * ks + 2 + (r & 1)], srcl);
      bB.u[r] = (g >> 1) ? vbB : vaB;
    }
    bregA[ks] = bA.s; bregB[ks] = bB.s;
  }

  // PV swapped, V fragments shared by both q-sets; l via ones-MFMA
  __builtin_amdgcn_s_setprio(1);
  #pragma unroll
  for (int dt = 0; dt < 4; ++dt){
    int rr = dt * 16 + l15;
    short8 v0 = *(const short8*)(vsb + rr * 64 + ((g ^ rx) << 3));
    short8 v1 = *(const short8*)(vsb + rr * 64 + (((4 + g) ^ rx) << 3));
    oA[dt] = MFMA16(v0, bregA[0], oA[dt]);
    oA[dt] = MFMA16(v1, bregA[1], oA[dt]);
    oB[dt] = MFMA16(v0, bregB[0], oB[dt]);
    oB[dt] = MFMA16(v1, bregB[1], oB[dt]);
  }
  olA = MFMA16(ones, bregA[0], olA);
  olA = MFMA16(ones, bregA[1], olA);
  olB = MFMA16(ones, bregB[0], olB);
  olB = MFMA16(ones, bregB[1], olB);
  __builtin_amdgcn_s_setprio(0);
  SB0();
  __builtin_amdgcn_s_barrier();
}

// grid (32, 32): x = q-block (128 rows, 4 waves x 32), y = bh
__global__ __launch_bounds__(256) void attn_k(const u16* __restrict__ q_s, const u16* __restrict__ k_s,
                                              const u16* __restrict__ vt_s, u16* __restrict__ net){
  __shared__ __align__(16) u16 Ks[2][64 * 64];
  __shared__ __align__(16) u16 Vt[2][64 * 64];
  const int tid = threadIdx.x, lane = tid & 63, wave = tid >> 6;
  const int l15 = lane & 15, g = lane >> 4, rx = l15 & 7;
  const int bh = blockIdx.y;
  const u16* kb  = k_s  + (size_t)bh * NKV * HD;
  const u16* vtb = vt_s + (size_t)bh * HD * NKV;
  const int q0 = blockIdx.x * 128 + wave * 32;
  const u16* qrow = q_s + ((size_t)bh * NQ + q0 + l15) * HD + g * 8;
  short8 qf[4];
  qf[0] = *(const short8*)(qrow);
  qf[1] = *(const short8*)(qrow + 32);
  qf[2] = *(const short8*)(qrow + 16 * HD);
  qf[3] = *(const short8*)(qrow + 16 * HD + 32);
  const short8 ones = {0x3F80, 0x3F80, 0x3F80, 0x3F80, 0x3F80, 0x3F80, 0x3F80, 0x3F80};

  // per-lane pre-swizzled global staging addresses (chunk ^= row&7; LDS stays linear)
  const int swz8 = (((tid & 7) ^ ((tid >> 3) & 7)) << 3);
  const u16* ak0 = kb  + (size_t)(tid >> 3) * 64   + swz8;
  const u16* av0 = vtb + (size_t)(tid >> 3) * 1024 + swz8;

  f32x4 oA[4] = {}, oB[4] = {};
  f32x4 olA = {}, olB = {};

  // prologue: stage tile 0 into buf 0
  gll16(ak0,             &Ks[0][wave * 512]);
  gll16(ak0 + 2048,      &Ks[0][2048 + wave * 512]);
  gll16(av0,             &Vt[0][wave * 512]);
  gll16(av0 + 32 * 1024, &Vt[0][2048 + wave * 512]);

  for (int tt = 0; tt < 7; ++tt){
    attn_tile<false>(&Ks[0][0], &Vt[0][0], &Ks[1][wave * 512], &Vt[1][wave * 512],
                     ak0 + (size_t)(2 * tt + 1) * 4096, av0 + (2 * tt + 1) * 64,
                     qf, ones, l15, g, rx, oA, oB, olA, olB);
    attn_tile<false>(&Ks[1][0], &Vt[1][0], &Ks[0][wave * 512], &Vt[0][wave * 512],
                     ak0 + (size_t)(2 * tt + 2) * 4096, av0 + (2 * tt + 2) * 64,
                     qf, ones, l15, g, rx, oA, oB, olA, olB);
  }
  attn_tile<false>(&Ks[0][0], &Vt[0][0], &Ks[1][wave * 512], &Vt[1][wave * 512],
                   ak0 + (size_t)15 * 4096, av0 + 15 * 64,
                   qf, ones, l15, g, rx, oA, oB, olA, olB);
  attn_tile<true>(&Ks[1][0], &Vt[1][0], nullptr, nullptr, nullptr, nullptr,
                  qf, ones, l15, g, rx, oA, oB, olA, olB);

  float invA = 1.f / olA[0], invB = 1.f / olB[0];
  int b = bh >> 3, h = bh & 7;
  size_t obaseA = ((size_t)b * NQ + q0 + l15) * 512 + h * 64 + g * 4;
  size_t obaseB = obaseA + (size_t)16 * 512;
  #pragma unroll
  for (int dt = 0; dt < 4; ++dt){
    uint2 pkA, pkB;
    pkA.x = cvtpk(oA[dt][0] * invA, oA[dt][1] * invA);
    pkA.y = cvtpk(oA[dt][2] * invA, oA[dt][3] * invA);
    *(uint2*)(net + obaseA + dt * 16) = pkA;
    pkB.x = cvtpk(oB[dt][0] * invB, oB[dt][1] * invB);
    pkB.y = cvtpk(oB[dt][2] * invB, oB[dt][3] * invB);
    *(uint2*)(net + obaseB + dt * 16) = pkB;
  }
}

extern "C" void kernel_launch(void* const* d_in, const int* in_sizes, int n_in,
                              void* d_out, int out_size, void* d_ws, size_t ws_size,
                              hipStream_t stream){
  const float* x      = (const float*)d_in[0];
  const float* q_w    = (const float*)d_in[1];
  const float* kv_w   = (const float*)d_in[2];
  const float* proj_w = (const float*)d_in[3];
  const float* proj_b = (const float*)d_in[4];
  const float* sr_w   = (const float*)d_in[5];
  const float* sr_b   = (const float*)d_in[6];
  const float* ln_w   = (const float*)d_in[7];
  const float* ln_b   = (const float*)d_in[8];
  (void)in_sizes; (void)n_in; (void)out_size; (void)ws_size;

  char* ws = (char*)d_ws;
  u16*   x_bf    = (u16*)(ws);                               // 0..16 MB (dead after q GEMM)
  float* xr_pre2 = (float*)(ws);                             // conv partials z2,z3 (0..16 MB)
  u16*   a_conv  = (u16*)(ws + ((size_t)16 << 20));          // 16..32 MB (dead after conv)
  u16*   xr      = (u16*)(ws + ((size_t)16 << 20));          // 16..20 MB (dead after kv gemm)
  u16*   net     = (u16*)(ws + ((size_t)16 << 20));          // 16..32 MB (attn output)
  u16*   q_sb    = (u16*)(ws + ((size_t)32 << 20));          // 32..48 MB
  float* xr_pre  = (float*)(ws + ((size_t)48 << 20));        // conv partials z0,z1 (48..64 MB)
  u16*   k_sb    = (u16*)(ws + ((size_t)48 << 20));          // 48..52 MB (after ln)
  u16*   vt_sb   = (u16*)(ws + ((size_t)52 << 20));          // 52..56 MB (V^T [bh][d][p])
  u16*   q_wT    = (u16*)(ws + ((size_t)64 << 20));
  u16*   kv_wT   = (u16*)(ws + ((size_t)64 << 20) + 524288);
  u16*   proj_wT = (u16*)(ws + ((size_t)64 << 20) + 524288 + 1048576);
  u16*   conv_BT = (u16*)(ws + ((size_t)64 << 20) + 524288 + 1048576 + 524288);
  float* out = (float*)d_out;

  prep_w<<<8192, 256, 0, stream>>>(q_w, kv_w, proj_w, sr_w, q_wT, kv_wT, proj_wT, conv_BT);
  prep_x<<<4096, 256, 0, stream>>>(x, x_bf, a_conv);
  gemm_bt<1><<<dim3(4, 128), 256, 0, stream>>>(x_bf, q_wT, nullptr, nullptr, q_sb, nullptr, nullptr, 16384, 512, 512);
  gemm_bt<0><<<dim3(4, 32, 4), 256, 0, stream>>>(a_conv, conv_BT, xr_pre, xr_pre2, nullptr, nullptr, sr_b, 4096, 512, 2048);
  ln_k<<<1024, 256, 0, stream>>>(xr_pre, xr_pre2, ln_w, ln_b, xr);
  gemm_bt<2><<<dim3(8, 32),  256, 0, stream>>>(xr, kv_wT, nullptr, nullptr, k_sb, vt_sb, nullptr, 4096, 1024, 512);
  attn_k<<<dim3(32, 32), 256, 0, stream>>>(q_sb, k_sb, vt_sb, net);
  gemm_bt<0><<<dim3(4, 128), 256, 0, stream>>>(net, proj_wT, out, nullptr, nullptr, nullptr, proj_b, 16384, 512, 512);
}

// Round 6
// 147.499 us; speedup vs baseline: 1.9678x; 1.1530x over previous
//
#include <hip/hip_runtime.h>
#include <cstdint>

#define HEADS 8
#define HD 64
#define NQ 4096
#define NKV 1024

typedef unsigned short u16;
typedef __attribute__((ext_vector_type(8))) short short8;
typedef __attribute__((ext_vector_type(4))) float f32x4;
typedef __attribute__((ext_vector_type(16))) float f32x16;

__device__ __forceinline__ u16 f2bf(float f){
  union { float f; unsigned u; } c; c.f = f;
  unsigned r = c.u + 0x7fffu + ((c.u >> 16) & 1u);
  return (u16)(r >> 16);
}
__device__ __forceinline__ unsigned pack2(float a, float b){
  return (unsigned)f2bf(a) | ((unsigned)f2bf(b) << 16);
}
__device__ __forceinline__ float fexp2(float x){
  float r;
  asm("v_exp_f32 %0, %1" : "=v"(r) : "v"(x));
  return r;
}
__device__ __forceinline__ unsigned cvtpk(float a, float b){
  unsigned r;
  asm("v_cvt_pk_bf16_f32 %0, %1, %2" : "=v"(r) : "v"(a), "v"(b));
  return r;
}
__device__ __forceinline__ void gll16(const void* g, void* l){
  __builtin_amdgcn_global_load_lds((const __attribute__((address_space(1))) unsigned*)g,
                                   (__attribute__((address_space(3))) unsigned*)l, 16, 0, 0);
}
#define SB0() __builtin_amdgcn_sched_barrier(0)
#define MFMA16(a, b, c) __builtin_amdgcn_mfma_f32_16x16x32_bf16(a, b, c, 0, 0, 0)
#define MFMA32(a, b, c) __builtin_amdgcn_mfma_f32_32x32x16_bf16(a, b, c, 0, 0, 0)
#define Z16 {0.f,0.f,0.f,0.f,0.f,0.f,0.f,0.f,0.f,0.f,0.f,0.f,0.f,0.f,0.f,0.f}

// ---- prep: x -> bf16 (both token layout and conv-patch layout) ----
__global__ __launch_bounds__(256) void prep_x(const float* __restrict__ x,
                                              u16* __restrict__ x_bf,
                                              u16* __restrict__ a_conv){
  int tid = blockIdx.x * 256 + threadIdx.x;
  int b   = tid >> 18;
  int rem = tid & 262143;
  int pos = rem >> 6;
  int ci0 = (rem & 63) << 3;
  size_t src = ((size_t)(b * NQ + pos)) * 512 + ci0;
  const float4* s4 = (const float4*)(x + src);
  float4 v0 = s4[0], v1 = s4[1];
  uint4 p;
  p.x = pack2(v0.x, v0.y); p.y = pack2(v0.z, v0.w);
  p.z = pack2(v1.x, v1.y); p.w = pack2(v1.z, v1.w);
  *(uint4*)(x_bf + src) = p;
  int h = pos >> 6, w = pos & 63;
  int pr = (h >> 1) * 32 + (w >> 1);
  int t  = (h & 1) * 2 + (w & 1);
  *(uint4*)(a_conv + ((size_t)(b * NKV + pr)) * 2048 + t * 512 + ci0) = p;
}

// ---- prep: weights -> bf16, transposed to [N][K] ----
__global__ __launch_bounds__(256) void prep_w(const float* __restrict__ q_w,
                                              const float* __restrict__ kv_w,
                                              const float* __restrict__ proj_w,
                                              const float* __restrict__ sr_w,
                                              u16* __restrict__ q_wT, u16* __restrict__ kv_wT,
                                              u16* __restrict__ proj_wT, u16* __restrict__ conv_BT){
  int e = blockIdx.x * 256 + threadIdx.x;
  if (e < 262144){ int n = e >> 9, k = e & 511; q_wT[e] = f2bf(q_w[k * 512 + n]); return; }
  e -= 262144;
  if (e < 524288){ int n = e >> 9, k = e & 511; kv_wT[e] = f2bf(kv_w[k * 1024 + n]); return; }
  e -= 524288;
  if (e < 262144){ int n = e >> 9, k = e & 511; proj_wT[e] = f2bf(proj_w[k * 512 + n]); return; }
  e -= 262144;
  { int co = e >> 11, r = e & 2047, t = r >> 9, ci = r & 511;
    conv_BT[e] = f2bf(sr_w[co * 2048 + ci * 4 + t]); }
}

// ---- GEMM: C[M,N] = A[M,K] @ BT[N,K]^T,  128x128 tile, BK=64, 4 waves ----
// LDS tiles XOR-swizzled (chunk ^= row&7) via pre-swizzled global source.
// Split-K via gridDim.z; z partials 0,1 -> Cf, 2,3 -> Cf2; bias only z==0.
// MODE 0: fp32 out (+bias).  MODE 1: q scatter (bf16, *0.125*log2e).
// MODE 2: k scatter + v^T scatter with kv quad-permutation pi (quads 1<->2 per 16-block).
template<int MODE>
__global__ __launch_bounds__(256) void gemm_bt(const u16* __restrict__ A, const u16* __restrict__ BT,
                                               float* __restrict__ Cf, float* __restrict__ Cf2,
                                               u16* __restrict__ Cb0,
                                               u16* __restrict__ Cb1, const float* __restrict__ bias,
                                               int M, int N, int K){
  __shared__ __align__(16) u16 As[128 * 64];
  __shared__ __align__(16) u16 Bs[128 * 64];
  const int tid = threadIdx.x, lane = tid & 63, wave = tid >> 6;
  const int l15 = lane & 15, g = lane >> 4, r7 = l15 & 7;
  const int m0 = blockIdx.y * 128, n0 = blockIdx.x * 128;
  const int wr = wave >> 1, wc = wave & 1;
  const int kz = blockIdx.z;
  const int klen = K / (int)gridDim.z;
  const int kb = kz * klen;
  f32x4 acc[4][4] = {};
  for (int kt = kb; kt < kb + klen; kt += 64){
    #pragma unroll
    for (int i = 0; i < 4; ++i){
      int c = i * 256 + tid;
      int row = c >> 3, sc = (c & 7) ^ (row & 7);
      gll16(A  + (size_t)(m0 + row) * K + kt + sc * 8, As + (size_t)(i * 256 + wave * 64) * 8);
      gll16(BT + (size_t)(n0 + row) * K + kt + sc * 8, Bs + (size_t)(i * 256 + wave * 64) * 8);
    }
    __syncthreads();
    #pragma unroll
    for (int kk = 0; kk < 2; ++kk){
      short8 af[4];
      #pragma unroll
      for (int mi = 0; mi < 4; ++mi)
        af[mi] = *(const short8*)(As + (wr * 64 + mi * 16 + l15) * 64 + (((kk * 4 + g) ^ r7) << 3));
      #pragma unroll
      for (int ni = 0; ni < 4; ++ni){
        short8 bf = *(const short8*)(Bs + (wc * 64 + ni * 16 + l15) * 64 + (((kk * 4 + g) ^ r7) << 3));
        #pragma unroll
        for (int mi = 0; mi < 4; ++mi)
          acc[mi][ni] = MFMA16(af[mi], bf, acc[mi][ni]);
      }
    }
    __syncthreads();
  }
  #pragma unroll
  for (int mi = 0; mi < 4; ++mi){
    int row = m0 + wr * 64 + mi * 16 + (lane >> 4) * 4;
    #pragma unroll
    for (int ni = 0; ni < 4; ++ni){
      int col = n0 + wc * 64 + ni * 16 + l15;
      f32x4 v = acc[mi][ni];
      if (MODE == 0){
        float* Co = (kz < 2) ? (Cf + (size_t)kz * M * N) : (Cf2 + (size_t)(kz - 2) * M * N);
        float bb = (bias && kz == 0) ? bias[col] : 0.f;
        #pragma unroll
        for (int j = 0; j < 4; ++j) Co[(size_t)(row + j) * N + col] = v[j] + bb;
      } else if (MODE == 1){
        int h = col >> 6, d = col & 63;
        #pragma unroll
        for (int j = 0; j < 4; ++j){
          int r = row + j, b = r >> 12, nq = r & 4095;
          Cb0[(((size_t)(b * HEADS + h)) * NQ + nq) * HD + d] = f2bf(v[j] * 0.18033688f);
        }
      } else {
        int s = col >> 9, h = (col >> 6) & 7, d = col & 63;
        if (s == 0){
          #pragma unroll
          for (int j = 0; j < 4; ++j){
            int r = row + j, b = r >> 10, p = r & 1023;
            Cb0[(((size_t)(b * HEADS + h)) * NKV + p) * HD + d] = f2bf(v[j]);
          }
        } else {                // V^T: [bh][d][pi(p)], pi = swap quads 1<->2 per 16-block
          int b = row >> 10, p0 = row & 1023;
          int pp = (p0 & ~12) | (((p0 >> 2) & 1) << 3) | (((p0 >> 3) & 1) << 2);
          ushort4 pk;
          pk.x = f2bf(v[0]); pk.y = f2bf(v[1]); pk.z = f2bf(v[2]); pk.w = f2bf(v[3]);
          *(ushort4*)(Cb1 + (((size_t)(b * HEADS + h)) * HD + d) * NKV + pp) = pk;
        }
      }
    }
  }
}

// ---- LayerNorm over 512 cols; sums four split-K partials; fp32 in, bf16 out ----
__global__ __launch_bounds__(256) void ln_k(const float* __restrict__ xp, const float* __restrict__ xp2,
                                            const float* __restrict__ w,
                                            const float* __restrict__ bias, u16* __restrict__ xr){
  int row = blockIdx.x * 4 + (threadIdx.x >> 6);
  int lane = threadIdx.x & 63;
  const float* s1 = xp  + (size_t)row * 512;
  const float* s2 = s1 + (size_t)4096 * 512;
  const float* s3 = xp2 + (size_t)row * 512;
  const float* s4 = s3 + (size_t)4096 * 512;
  float vals[8]; float s = 0.f, ss = 0.f;
  #pragma unroll
  for (int j = 0; j < 8; ++j){
    int c = lane + j * 64;
    float v = (s1[c] + s2[c]) + (s3[c] + s4[c]);
    vals[j] = v; s += v; ss += v * v;
  }
  #pragma unroll
  for (int off = 32; off >= 1; off >>= 1){ s += __shfl_xor(s, off); ss += __shfl_xor(ss, off); }
  float mean = s * (1.f / 512.f);
  float var  = ss * (1.f / 512.f) - mean * mean;
  float rs = rsqrtf(var + 1e-5f);
  u16* dst = xr + (size_t)row * 512;
  #pragma unroll
  for (int j = 0; j < 8; ++j){
    int c = lane + j * 64;
    dst[c] = f2bf((vals[j] - mean) * rs * w[c] + bias[c]);
  }
}

// ---- flash attention v5: 32x32 MFMA, zero-shuffle PV (pi-permuted V), no-max exp2 ----
// q pre-scaled by (1/8)*log2(e) so p = 2^s. Wave owns 32 q-rows (q = lane&31).
template<bool LAST>
__device__ __forceinline__ void attn_tile(const u16* ksb, const u16* vsb,
                                          u16* kstage, u16* vstage,
                                          const u16* akg, const u16* avg,
                                          const short8* qf,
                                          int l31, int hi, int x7,
                                          f32x16* o, float& l_run){
  SB0();
  if (!LAST){
    gll16(akg,              kstage);
    gll16(akg + 2048,       kstage + 2048);
    gll16(avg,              vstage);
    gll16(avg + 32 * 1024,  vstage + 2048);
    SB0();
    asm volatile("s_waitcnt vmcnt(4)" ::: "memory");
  } else {
    asm volatile("s_waitcnt vmcnt(0)" ::: "memory");
  }
  __builtin_amdgcn_s_barrier();
  SB0();

  // QK^T swapped: S^T[kv(64)][q(32)] = two 32x32 tiles, K=64 over d
  f32x16 sa[2];
  __builtin_amdgcn_s_setprio(1);
  #pragma unroll
  for (int sub = 0; sub < 2; ++sub){
    f32x16 a = Z16;
    #pragma unroll
    for (int ks = 0; ks < 4; ++ks){
      short8 kf = *(const short8*)(ksb + (sub * 32 + l31) * 64 + (((ks * 2 + hi) ^ x7) << 3));
      a = MFMA32(kf, qf[ks], a);
    }
    sa[sub] = a;
  }
  __builtin_amdgcn_s_setprio(0);

  // p = 2^s, packed to bf16 pairs; row-sum folded in (l is per-q, split across hi)
  unsigned w[16];
  float ps = 0.f;
  #pragma unroll
  for (int sub = 0; sub < 2; ++sub)
    #pragma unroll
    for (int t = 0; t < 8; ++t){
      float p0 = fexp2(sa[sub][2 * t]), p1 = fexp2(sa[sub][2 * t + 1]);
      ps += p0 + p1;
      w[sub * 8 + t] = cvtpk(p0, p1);
    }
  l_run += ps;

  // PV swapped: O^T[d][q] += V^T x P^T. V cols are pi-permuted so w-pairs ARE the B-frags.
  __builtin_amdgcn_s_setprio(1);
  #pragma unroll
  for (int dt = 0; dt < 2; ++dt)
    #pragma unroll
    for (int sl = 0; sl < 4; ++sl){
      short8 vf = *(const short8*)(vsb + (dt * 32 + l31) * 64 + (((sl * 2 + hi) ^ x7) << 3));
      union { unsigned u[4]; short8 s; } bb;
      bb.u[0] = w[sl * 4 + 0]; bb.u[1] = w[sl * 4 + 1];
      bb.u[2] = w[sl * 4 + 2]; bb.u[3] = w[sl * 4 + 3];
      o[dt] = MFMA32(vf, bb.s, o[dt]);
    }
  __builtin_amdgcn_s_setprio(0);
  SB0();
  __builtin_amdgcn_s_barrier();
}

// grid (32, 32): x = q-block (128 rows, 4 waves x 32), y = bh
__global__ __launch_bounds__(256) void attn_k(const u16* __restrict__ q_s, const u16* __restrict__ k_s,
                                              const u16* __restrict__ vt_s, u16* __restrict__ net){
  __shared__ __align__(16) u16 Ks[2][64 * 64];
  __shared__ __align__(16) u16 Vt[2][64 * 64];
  const int tid = threadIdx.x, lane = tid & 63, wave = tid >> 6;
  const int l31 = lane & 31, hi = lane >> 5, x7 = lane & 7;
  const int bh = blockIdx.y;
  const u16* kb  = k_s  + (size_t)bh * NKV * HD;
  const u16* vtb = vt_s + (size_t)bh * HD * NKV;
  const int q0 = blockIdx.x * 128 + wave * 32;
  const u16* qbase = q_s + ((size_t)bh * NQ + q0 + l31) * HD + hi * 8;
  short8 qf[4];
  #pragma unroll
  for (int ks = 0; ks < 4; ++ks) qf[ks] = *(const short8*)(qbase + ks * 16);

  // per-lane pre-swizzled global staging addresses (chunk ^= row&7; LDS stays linear)
  const int swz8 = (((tid & 7) ^ ((tid >> 3) & 7)) << 3);
  const u16* ak0 = kb  + (size_t)(tid >> 3) * 64   + swz8;
  const u16* av0 = vtb + (size_t)(tid >> 3) * 1024 + swz8;

  f32x16 o[2] = { Z16, Z16 };
  float l_run = 0.f;

  // prologue: stage tile 0 into buf 0
  gll16(ak0,             &Ks[0][wave * 512]);
  gll16(ak0 + 2048,      &Ks[0][2048 + wave * 512]);
  gll16(av0,             &Vt[0][wave * 512]);
  gll16(av0 + 32 * 1024, &Vt[0][2048 + wave * 512]);

  for (int tt = 0; tt < 7; ++tt){
    attn_tile<false>(&Ks[0][0], &Vt[0][0], &Ks[1][wave * 512], &Vt[1][wave * 512],
                     ak0 + (size_t)(2 * tt + 1) * 4096, av0 + (2 * tt + 1) * 64,
                     qf, l31, hi, x7, o, l_run);
    attn_tile<false>(&Ks[1][0], &Vt[1][0], &Ks[0][wave * 512], &Vt[0][wave * 512],
                     ak0 + (size_t)(2 * tt + 2) * 4096, av0 + (2 * tt + 2) * 64,
                     qf, l31, hi, x7, o, l_run);
  }
  attn_tile<false>(&Ks[0][0], &Vt[0][0], &Ks[1][wave * 512], &Vt[1][wave * 512],
                   ak0 + (size_t)15 * 4096, av0 + 15 * 64,
                   qf, l31, hi, x7, o, l_run);
  attn_tile<true>(&Ks[1][0], &Vt[1][0], nullptr, nullptr, nullptr, nullptr,
                  qf, l31, hi, x7, o, l_run);

  float l = l_run + __shfl_xor(l_run, 32);
  float inv = 1.f / l;
  int b = bh >> 3, h = bh & 7;
  size_t obase = ((size_t)b * NQ + q0 + l31) * 512 + h * 64;
  #pragma unroll
  for (int dt = 0; dt < 2; ++dt)
    #pragma unroll
    for (int t = 0; t < 8; ++t){
      int j = 2 * t;
      int d = dt * 32 + (j & 3) + 8 * (j >> 2) + 4 * hi;
      *(unsigned*)(net + obase + d) = cvtpk(o[dt][j] * inv, o[dt][j + 1] * inv);
    }
}

extern "C" void kernel_launch(void* const* d_in, const int* in_sizes, int n_in,
                              void* d_out, int out_size, void* d_ws, size_t ws_size,
                              hipStream_t stream){
  const float* x      = (const float*)d_in[0];
  const float* q_w    = (const float*)d_in[1];
  const float* kv_w   = (const float*)d_in[2];
  const float* proj_w = (const float*)d_in[3];
  const float* proj_b = (const float*)d_in[4];
  const float* sr_w   = (const float*)d_in[5];
  const float* sr_b   = (const float*)d_in[6];
  const float* ln_w   = (const float*)d_in[7];
  const float* ln_b   = (const float*)d_in[8];
  (void)in_sizes; (void)n_in; (void)out_size; (void)ws_size;

  char* ws = (char*)d_ws;
  u16*   x_bf    = (u16*)(ws);                               // 0..16 MB (dead after q GEMM)
  float* xr_pre2 = (float*)(ws);                             // conv partials z2,z3 (0..16 MB)
  u16*   a_conv  = (u16*)(ws + ((size_t)16 << 20));          // 16..32 MB (dead after conv)
  u16*   xr      = (u16*)(ws + ((size_t)16 << 20));          // 16..20 MB (dead after kv gemm)
  u16*   net     = (u16*)(ws + ((size_t)16 << 20));          // 16..32 MB (attn output)
  u16*   q_sb    = (u16*)(ws + ((size_t)32 << 20));          // 32..48 MB
  float* xr_pre  = (float*)(ws + ((size_t)48 << 20));        // conv partials z0,z1 (48..64 MB)
  u16*   k_sb    = (u16*)(ws + ((size_t)48 << 20));          // 48..52 MB (after ln)
  u16*   vt_sb   = (u16*)(ws + ((size_t)52 << 20));          // 52..56 MB (V^T [bh][d][pi(p)])
  u16*   q_wT    = (u16*)(ws + ((size_t)64 << 20));
  u16*   kv_wT   = (u16*)(ws + ((size_t)64 << 20) + 524288);
  u16*   proj_wT = (u16*)(ws + ((size_t)64 << 20) + 524288 + 1048576);
  u16*   conv_BT = (u16*)(ws + ((size_t)64 << 20) + 524288 + 1048576 + 524288);
  float* out = (float*)d_out;

  prep_w<<<8192, 256, 0, stream>>>(q_w, kv_w, proj_w, sr_w, q_wT, kv_wT, proj_wT, conv_BT);
  prep_x<<<4096, 256, 0, stream>>>(x, x_bf, a_conv);
  gemm_bt<1><<<dim3(4, 128), 256, 0, stream>>>(x_bf, q_wT, nullptr, nullptr, q_sb, nullptr, nullptr, 16384, 512, 512);
  gemm_bt<0><<<dim3(4, 32, 4), 256, 0, stream>>>(a_conv, conv_BT, xr_pre, xr_pre2, nullptr, nullptr, sr_b, 4096, 512, 2048);
  ln_k<<<1024, 256, 0, stream>>>(xr_pre, xr_pre2, ln_w, ln_b, xr);
  gemm_bt<2><<<dim3(8, 32),  256, 0, stream>>>(xr, kv_wT, nullptr, nullptr, k_sb, vt_sb, nullptr, 4096, 1024, 512);
  attn_k<<<dim3(32, 32), 256, 0, stream>>>(q_sb, k_sb, vt_sb, net);
  gemm_bt<0><<<dim3(4, 128), 256, 0, stream>>>(net, proj_wT, out, nullptr, nullptr, nullptr, proj_b, 16384, 512, 512);
}